// Round 4
// baseline (337.093 us; speedup 1.0000x reference)
//
#include <hip/hip_runtime.h>
#include <math.h>

namespace {

constexpr int TSTEPS = 512;
constexpr int F_IN   = 25;
constexpr int H_DIM  = 64;
constexpr int TILE_B = 16;
constexpr int NTHR   = 512;   // 8 waves: (unit-block 0..3) x (row-half 0..1)
// K layout: [0,25) = x, [25,89) = h, 89 = bias-one, [90,96) = zero pad
// A-fragment buffer: [2 bufs][3 ksteps][64 lanes][8 bf16], fragment-ordered:
//   slot (s, lane, j) holds A[row = lane&15][k = s*32 + (lane>>4)*8 + j]

typedef __attribute__((ext_vector_type(8))) short bf16x8;
typedef __attribute__((ext_vector_type(4))) float f32x4;

constexpr float LOG2E  = 1.4426950408889634f;
constexpr float LOG2E2 = 2.8853900817779268f;

__device__ __forceinline__ short f2bf(float f) {  // round-to-nearest-even (setup only)
    unsigned u = __float_as_uint(f);
    unsigned r = (u + 0x7FFFu + ((u >> 16) & 1u)) >> 16;
    return (short)r;
}
__device__ __forceinline__ float bf2f(short s) {
    return __uint_as_float(((unsigned)(unsigned short)s) << 16);
}
__device__ __forceinline__ unsigned cvt_pk_bf16(float lo, float hi) {
    unsigned r;
    asm("v_cvt_pk_bf16_f32 %0, %1, %2" : "=v"(r) : "v"(lo), "v"(hi));
    return r;
}
__device__ __forceinline__ float exp2_neg(float x) {      // 2^(-x)
    float r;
    asm("v_exp_f32 %0, -%1" : "=v"(r) : "v"(x));
    return r;
}
__device__ __forceinline__ float exp2_negabs(float x) {   // 2^(-|x|)
    float r;
    asm("v_exp_f32 %0, -abs(%1)" : "=v"(r) : "v"(x));
    return r;
}

// Pre-scaled cell: z' = log2e*z for i,f,o ; z' = 2*log2e*z for g.
//   sigmoid(z) = 1/(1+2^-z') ; tanh pair shares denominators; 5 exp + 3 rcp.
__device__ __forceinline__ float lstm_cell(float zi, float zf, float zg, float zo, float& c) {
    const float ei = exp2_neg(zi);
    const float ef = exp2_neg(zf);
    const float eg = exp2_negabs(zg);
    const float eo = exp2_neg(zo);
    const float r1 = __builtin_amdgcn_rcpf((1.0f + ei) * (1.0f + eg));
    const float ig = copysignf((1.0f - eg) * r1, zg);
    const float f  = __builtin_amdgcn_rcpf(1.0f + ef);
    const float cn = fmaf(c, f, ig);
    c = cn;
    const float ec = exp2_negabs(cn * LOG2E2);
    const float r3 = __builtin_amdgcn_rcpf((1.0f + eo) * (1.0f + ec));
    return copysignf((1.0f - ec) * r3, cn);
}

__global__ __launch_bounds__(NTHR, 2)
void lstm_mfma(const float* __restrict__ x,     // [B, T, F]
               const float* __restrict__ Wx_w,  // [256, 25]
               const float* __restrict__ Wx_b,  // [256]
               const float* __restrict__ Wh_w,  // [256, 64]
               const float* __restrict__ Wh_b,  // [256]
               const float* __restrict__ fc_w,  // [64]
               const float* __restrict__ fc_b,  // [1]
               float* __restrict__ out)         // [B]
{
    __shared__ short a_buf[2][3][64][8];   // 6144 B
    __shared__ float red[4][16];

    const int tid  = threadIdx.x;
    const int l    = tid & 63;
    const int wvf  = tid >> 6;       // 0..7
    const int wv   = wvf & 3;        // unit-block: units [wv*16, wv*16+16)
    const int half = wvf >> 2;       // row-half: cell rows lhi*4 + 2*half + {0,1}
    const int lrow = l & 15;
    const int lhi  = l >> 4;
    const int row0 = blockIdx.x * TILE_B;

    // ---- W^T B-fragments (hi/lo split, log2e pre-scaled): 24 frags/wave ----
    bf16x8 w_hi[4][3], w_lo[4][3];
    #pragma unroll
    for (int g = 0; g < 4; ++g) {
        const int col = g * 64 + wv * 16 + lrow;
        const float scale = (g == 2) ? LOG2E2 : LOG2E;   // gate order i,f,g,o
        #pragma unroll
        for (int s = 0; s < 3; ++s) {
            bf16x8 hi, lo;
            #pragma unroll
            for (int j = 0; j < 8; ++j) {
                const int k = s * 32 + lhi * 8 + j;
                float val;
                if (k < F_IN)           val = Wx_w[col * F_IN + k];
                else if (k < 89)        val = Wh_w[col * H_DIM + (k - F_IN)];
                else if (k == 89)       val = Wx_b[col] + Wh_b[col];   // fused bias
                else                    val = 0.0f;
                val *= scale;
                const short h16 = f2bf(val);
                hi[j] = h16;
                lo[j] = f2bf(val - bf2f(h16));
            }
            w_hi[g][s] = hi;
            w_lo[g][s] = lo;
        }
    }

    // ---- init a_buf: zeros, bias-one at k==89 (both buffers) ----
    for (int idx = tid; idx < 2 * 3 * 64 * 8; idx += NTHR) {
        const int j    = idx & 7;
        const int lane = (idx >> 3) & 63;
        const int s    = (idx >> 9) % 3;
        const int k    = s * 32 + (lane >> 4) * 8 + j;
        ((short*)a_buf)[idx] = (k == 89) ? (short)0x3F80 : (short)0;
    }
    __syncthreads();

    // ---- per-thread x slot (one element per thread, tid < 400) ----
    const bool xact  = tid < TILE_B * F_IN;
    const int  xrow  = xact ? tid / F_IN : 0;
    const int  xf    = xact ? tid % F_IN : 0;
    const float* xq0 = x + (size_t)(row0 + xrow) * TSTEPS * F_IN + xf;
    const int  xoff0 = ((xrow | ((xf >> 3) << 4)) * 8) + (xf & 7);
    short* const abase = &a_buf[0][0][0][0];

    // x[t=0] into buffer 0
    if (xact) abase[xoff0] = f2bf(xq0[0]);
    __syncthreads();
    xq0 += F_IN;   // -> t=1

    // ---- h-write slot mapping: k = 25 + unit, rows 2*half + {0,1} ----
    const int unit  = wv * 16 + lrow;
    const int kh    = F_IN + unit;
    const int sh    = kh >> 5;
    const int hbank = ((kh >> 3) & 3) << 4;
    const int jh    = kh & 7;

    const float fcw = fc_w[unit];
    float c0 = 0.f, c1 = 0.f;
    float hq0 = 0.f, hq1 = 0.f;

    for (int t = 0; t < TSTEPS; ++t) {
        const int p  = t & 1;
        const int pn = p ^ 1;

        // A fragments (broadcast b128, conflict-free)
        bf16x8 a0 = *(const bf16x8*)&a_buf[p][0][l][0];
        bf16x8 a1 = *(const bf16x8*)&a_buf[p][1][l][0];
        bf16x8 a2 = *(const bf16x8*)&a_buf[p][2][l][0];

        // prefetch x[t+1]
        float xv0 = 0.f;
        if ((t + 1 < TSTEPS) && xact) {
            xv0 = xq0[0];
            xq0 += F_IN;
        }

        // z' = v @ W'^T (hi+lo), acc[g][q] = z'[lhi*4+q][g*64+unit]
        f32x4 acc[4];
        #pragma unroll
        for (int g = 0; g < 4; ++g) {
            f32x4 a = {0.f, 0.f, 0.f, 0.f};
            a = __builtin_amdgcn_mfma_f32_16x16x32_bf16(a0, w_hi[g][0], a, 0, 0, 0);
            a = __builtin_amdgcn_mfma_f32_16x16x32_bf16(a0, w_lo[g][0], a, 0, 0, 0);
            a = __builtin_amdgcn_mfma_f32_16x16x32_bf16(a1, w_hi[g][1], a, 0, 0, 0);
            a = __builtin_amdgcn_mfma_f32_16x16x32_bf16(a1, w_lo[g][1], a, 0, 0, 0);
            a = __builtin_amdgcn_mfma_f32_16x16x32_bf16(a2, w_hi[g][2], a, 0, 0, 0);
            a = __builtin_amdgcn_mfma_f32_16x16x32_bf16(a2, w_lo[g][2], a, 0, 0, 0);
            acc[g] = a;
        }

        // this wave's 2 rows (half-uniform static selects; no dynamic vec index)
        float zi0 = half ? acc[0][2] : acc[0][0];
        float zi1 = half ? acc[0][3] : acc[0][1];
        float zf0 = half ? acc[1][2] : acc[1][0];
        float zf1 = half ? acc[1][3] : acc[1][1];
        float zg0 = half ? acc[2][2] : acc[2][0];
        float zg1 = half ? acc[2][3] : acc[2][1];
        float zo0 = half ? acc[3][2] : acc[3][0];
        float zo1 = half ? acc[3][3] : acc[3][1];

        hq0 = lstm_cell(zi0, zf0, zg0, zo0, c0);
        hq1 = lstm_cell(zi1, zf1, zg1, zo1, c1);

        // h -> a_buf[pn] (2 bf16 stores from one packed cvt)
        const unsigned u01 = cvt_pk_bf16(hq0, hq1);
        short* const hdst = &a_buf[pn][sh][0][0] + (hbank + lhi * 4 + 2 * half) * 8 + jh;
        hdst[0] = (short)(u01 & 0xffffu);
        hdst[8] = (short)(u01 >> 16);

        // x[t+1] -> a_buf[pn]
        if ((t + 1 < TSTEPS) && xact) {
            short* const xdst = abase + pn * (3 * 64 * 8);
            xdst[xoff0] = (short)(cvt_pk_bf16(xv0, xv0) & 0xffffu);
        }
        __syncthreads();
    }

    // ---- epilogue: logits = h_last @ fc_w + fc_b ----
    float p0 = hq0 * fcw;
    float p1 = hq1 * fcw;
    #pragma unroll
    for (int m = 1; m <= 8; m <<= 1) {
        p0 += __shfl_xor(p0, m);
        p1 += __shfl_xor(p1, m);
    }
    if (lrow == 0) {
        red[wv][lhi * 4 + 2 * half + 0] = p0;
        red[wv][lhi * 4 + 2 * half + 1] = p1;
    }
    __syncthreads();
    if (tid < TILE_B) {
        out[row0 + tid] = red[0][tid] + red[1][tid] + red[2][tid] + red[3][tid] + fc_b[0];
    }
}

} // namespace

extern "C" void kernel_launch(void* const* d_in, const int* in_sizes, int n_in,
                              void* d_out, int out_size, void* d_ws, size_t ws_size,
                              hipStream_t stream) {
    const float* x    = (const float*)d_in[0];
    // d_in[1] = mask: all-ones, use_masked_last=False -> unused
    const float* Wx_w = (const float*)d_in[2];
    const float* Wx_b = (const float*)d_in[3];
    const float* Wh_w = (const float*)d_in[4];
    const float* Wh_b = (const float*)d_in[5];
    const float* fc_w = (const float*)d_in[6];
    const float* fc_b = (const float*)d_in[7];
    float* out = (float*)d_out;

    const int B    = out_size;        // 4096
    const int grid = B / TILE_B;      // 256 blocks = 1 per CU

    lstm_mfma<<<grid, NTHR, 0, stream>>>(x, Wx_w, Wx_b, Wh_w, Wh_b, fc_w, fc_b, out);
}

// Round 5
// 306.380 us; speedup vs baseline: 1.1002x; 1.1002x over previous
//
#include <hip/hip_runtime.h>
#include <math.h>

namespace {

constexpr int TSTEPS = 512;
constexpr int F_IN   = 25;
constexpr int H_DIM  = 64;
constexpr int TILE_B = 16;
constexpr int NTHR   = 256;
// K layout: [0,25) = x, [25,89) = h, 89 = bias-one, [90,96) = zero pad
// A-fragment buffer: [2 bufs][3 ksteps][64 lanes][8 bf16], fragment-ordered:
//   slot (s, lane, j) holds A[row = lane&15][k = s*32 + (lane>>4)*8 + j]

typedef __attribute__((ext_vector_type(8))) short bf16x8;
typedef __attribute__((ext_vector_type(4))) float f32x4;

constexpr float LOG2E  = 1.4426950408889634f;
constexpr float LOG2E2 = 2.8853900817779268f;

__device__ __forceinline__ short f2bf(float f) {  // round-to-nearest-even (setup only)
    unsigned u = __float_as_uint(f);
    unsigned r = (u + 0x7FFFu + ((u >> 16) & 1u)) >> 16;
    return (short)r;
}
__device__ __forceinline__ float bf2f(short s) {
    return __uint_as_float(((unsigned)(unsigned short)s) << 16);
}
__device__ __forceinline__ unsigned cvt_pk_bf16(float lo, float hi) {
    unsigned r;
    asm("v_cvt_pk_bf16_f32 %0, %1, %2" : "=v"(r) : "v"(lo), "v"(hi));
    return r;
}
__device__ __forceinline__ float exp2_neg(float x) {      // 2^(-x)
    float r;
    asm("v_exp_f32 %0, -%1" : "=v"(r) : "v"(x));
    return r;
}
__device__ __forceinline__ float exp2_negabs(float x) {   // 2^(-|x|)
    float r;
    asm("v_exp_f32 %0, -abs(%1)" : "=v"(r) : "v"(x));
    return r;
}

// Pre-scaled cell: z' = log2e*z for i,f,o ; z' = 2*log2e*z for g.
//   sigmoid(z) = 1/(1+2^-z') ; tanh pair shares denominators; 5 exp + 3 rcp.
// Limits: z -> -inf gives e=inf, rcp(inf)=0 -> gate=0 (correct, no NaN).
__device__ __forceinline__ float lstm_cell(float zi, float zf, float zg, float zo, float& c) {
    const float ei = exp2_neg(zi);
    const float ef = exp2_neg(zf);
    const float eg = exp2_negabs(zg);
    const float eo = exp2_neg(zo);
    const float r1 = __builtin_amdgcn_rcpf((1.0f + ei) * (1.0f + eg));
    const float ig = copysignf((1.0f - eg) * r1, zg);
    const float f  = __builtin_amdgcn_rcpf(1.0f + ef);
    const float cn = fmaf(c, f, ig);
    c = cn;
    const float ec = exp2_negabs(cn * LOG2E2);
    const float r3 = __builtin_amdgcn_rcpf((1.0f + eo) * (1.0f + ec));
    return copysignf((1.0f - ec) * r3, cn);
}

__global__ __launch_bounds__(NTHR)
void lstm_mfma(const float* __restrict__ x,     // [B, T, F]
               const float* __restrict__ Wx_w,  // [256, 25]
               const float* __restrict__ Wx_b,  // [256]
               const float* __restrict__ Wh_w,  // [256, 64]
               const float* __restrict__ Wh_b,  // [256]
               const float* __restrict__ fc_w,  // [64]
               const float* __restrict__ fc_b,  // [1]
               float* __restrict__ out)         // [B]
{
    __shared__ short a_buf[2][3][64][8];   // 6144 B
    __shared__ float red[4][16];

    const int tid  = threadIdx.x;
    const int l    = tid & 63;
    const int wv   = tid >> 6;       // wave id: owns units [wv*16, wv*16+16) x 4 gates
    const int lrow = l & 15;
    const int lhi  = l >> 4;
    const int row0 = blockIdx.x * TILE_B;

    // ---- W^T B-fragments (hi/lo split, log2e pre-scaled): 24 frags = 96 VGPR ----
    bf16x8 w_hi[4][3], w_lo[4][3];
    #pragma unroll
    for (int g = 0; g < 4; ++g) {
        const int col = g * 64 + wv * 16 + lrow;   // gate-col this lane serves
        const float scale = (g == 2) ? LOG2E2 : LOG2E;   // gate order i,f,g,o
        #pragma unroll
        for (int s = 0; s < 3; ++s) {
            bf16x8 hi, lo;
            #pragma unroll
            for (int j = 0; j < 8; ++j) {
                const int k = s * 32 + lhi * 8 + j;
                float val;
                if (k < F_IN)           val = Wx_w[col * F_IN + k];
                else if (k < 89)        val = Wh_w[col * H_DIM + (k - F_IN)];
                else if (k == 89)       val = Wx_b[col] + Wh_b[col];   // fused bias
                else                    val = 0.0f;
                val *= scale;
                const short h16 = f2bf(val);
                hi[j] = h16;
                lo[j] = f2bf(val - bf2f(h16));
            }
            w_hi[g][s] = hi;
            w_lo[g][s] = lo;
        }
    }

    // ---- init a_buf: zeros, bias-one at k==89 (both buffers) ----
    for (int idx = tid; idx < 2 * 3 * 64 * 8; idx += NTHR) {
        const int j    = idx & 7;
        const int lane = (idx >> 3) & 63;
        const int s    = (idx >> 9) % 3;
        const int k    = s * 32 + (lane >> 4) * 8 + j;
        ((short*)a_buf)[idx] = (k == 89) ? (short)0x3F80 : (short)0;
    }
    __syncthreads();

    // ---- per-thread x slot mapping (constant across steps) ----
    // element e -> (row = e/25, f = e%25); slot: s=0, lane' = row | ((f>>3)<<4), j = f&7
    const int xrow0 = tid / F_IN,          xf0 = tid % F_IN;           // e0 = tid (<400 always)
    const int xrow1 = (tid + 256) / F_IN,  xf1 = (tid + 256) % F_IN;   // e1 valid iff tid<144
    const float* xq0 = x + (size_t)(row0 + xrow0) * TSTEPS * F_IN + xf0;
    const float* xq1 = x + (size_t)(row0 + (tid < 144 ? xrow1 : 0)) * TSTEPS * F_IN + xf1;
    const int xoff0 = ((xrow0 | ((xf0 >> 3) << 4)) * 8) + (xf0 & 7);
    const int xoff1 = ((xrow1 | ((xf1 >> 3) << 4)) * 8) + (xf1 & 7);
    short* const abase = &a_buf[0][0][0][0];

    // x[t=0] into buffer 0
    abase[xoff0] = f2bf(xq0[0]);
    if (tid < 144) abase[xoff1] = f2bf(xq1[0]);
    __syncthreads();

    // advance prefetch pointers to t=1
    xq0 += F_IN;
    xq1 += F_IN;

    // ---- h-write slot mapping (constant): k = 25 + unit ----
    const int unit  = wv * 16 + lrow;
    const int kh    = F_IN + unit;
    const int sh    = kh >> 5;
    const int hbank = ((kh >> 3) & 3) << 4;
    const int jh    = kh & 7;

    const float fcw = fc_w[unit];
    float c[4] = {0.f, 0.f, 0.f, 0.f};
    float hq[4] = {0.f, 0.f, 0.f, 0.f};

    for (int t = 0; t < TSTEPS; ++t) {
        const int p  = t & 1;
        const int pn = p ^ 1;

        // A fragments (conflict-free b128, all waves broadcast-read same region)
        bf16x8 a0 = *(const bf16x8*)&a_buf[p][0][l][0];
        bf16x8 a1 = *(const bf16x8*)&a_buf[p][1][l][0];
        bf16x8 a2 = *(const bf16x8*)&a_buf[p][2][l][0];

        // prefetch x[t+1] (latency hides under MFMA + gates)
        float xv0 = 0.f, xv1 = 0.f;
        if (t + 1 < TSTEPS) {
            xv0 = xq0[0];
            if (tid < 144) xv1 = xq1[0];
            xq0 += F_IN;
            xq1 += F_IN;
        }

        // z' = v @ W'^T (hi+lo). Four INDEPENDENT accumulator chains, issued
        // round-robin so the matrix pipe stays fed (round 3 had them serial:
        // 17 cyc/MFMA latency-bound). Per-acc accumulation order unchanged
        // (hi[s0], lo[s0], hi[s1], lo[s1], hi[s2], lo[s2]) -> bitwise same.
        f32x4 acc0 = {0.f, 0.f, 0.f, 0.f};
        f32x4 acc1 = {0.f, 0.f, 0.f, 0.f};
        f32x4 acc2 = {0.f, 0.f, 0.f, 0.f};
        f32x4 acc3 = {0.f, 0.f, 0.f, 0.f};

        acc0 = __builtin_amdgcn_mfma_f32_16x16x32_bf16(a0, w_hi[0][0], acc0, 0, 0, 0);
        acc1 = __builtin_amdgcn_mfma_f32_16x16x32_bf16(a0, w_hi[1][0], acc1, 0, 0, 0);
        acc2 = __builtin_amdgcn_mfma_f32_16x16x32_bf16(a0, w_hi[2][0], acc2, 0, 0, 0);
        acc3 = __builtin_amdgcn_mfma_f32_16x16x32_bf16(a0, w_hi[3][0], acc3, 0, 0, 0);

        acc0 = __builtin_amdgcn_mfma_f32_16x16x32_bf16(a0, w_lo[0][0], acc0, 0, 0, 0);
        acc1 = __builtin_amdgcn_mfma_f32_16x16x32_bf16(a0, w_lo[1][0], acc1, 0, 0, 0);
        acc2 = __builtin_amdgcn_mfma_f32_16x16x32_bf16(a0, w_lo[2][0], acc2, 0, 0, 0);
        acc3 = __builtin_amdgcn_mfma_f32_16x16x32_bf16(a0, w_lo[3][0], acc3, 0, 0, 0);

        acc0 = __builtin_amdgcn_mfma_f32_16x16x32_bf16(a1, w_hi[0][1], acc0, 0, 0, 0);
        acc1 = __builtin_amdgcn_mfma_f32_16x16x32_bf16(a1, w_hi[1][1], acc1, 0, 0, 0);
        acc2 = __builtin_amdgcn_mfma_f32_16x16x32_bf16(a1, w_hi[2][1], acc2, 0, 0, 0);
        acc3 = __builtin_amdgcn_mfma_f32_16x16x32_bf16(a1, w_hi[3][1], acc3, 0, 0, 0);

        acc0 = __builtin_amdgcn_mfma_f32_16x16x32_bf16(a1, w_lo[0][1], acc0, 0, 0, 0);
        acc1 = __builtin_amdgcn_mfma_f32_16x16x32_bf16(a1, w_lo[1][1], acc1, 0, 0, 0);
        acc2 = __builtin_amdgcn_mfma_f32_16x16x32_bf16(a1, w_lo[2][1], acc2, 0, 0, 0);
        acc3 = __builtin_amdgcn_mfma_f32_16x16x32_bf16(a1, w_lo[3][1], acc3, 0, 0, 0);

        acc0 = __builtin_amdgcn_mfma_f32_16x16x32_bf16(a2, w_hi[0][2], acc0, 0, 0, 0);
        acc1 = __builtin_amdgcn_mfma_f32_16x16x32_bf16(a2, w_hi[1][2], acc1, 0, 0, 0);
        acc2 = __builtin_amdgcn_mfma_f32_16x16x32_bf16(a2, w_hi[2][2], acc2, 0, 0, 0);
        acc3 = __builtin_amdgcn_mfma_f32_16x16x32_bf16(a2, w_hi[3][2], acc3, 0, 0, 0);

        acc0 = __builtin_amdgcn_mfma_f32_16x16x32_bf16(a2, w_lo[0][2], acc0, 0, 0, 0);
        acc1 = __builtin_amdgcn_mfma_f32_16x16x32_bf16(a2, w_lo[1][2], acc1, 0, 0, 0);
        acc2 = __builtin_amdgcn_mfma_f32_16x16x32_bf16(a2, w_lo[2][2], acc2, 0, 0, 0);
        acc3 = __builtin_amdgcn_mfma_f32_16x16x32_bf16(a2, w_lo[3][2], acc3, 0, 0, 0);

        // gates + c/h update (acc_g[q] = z'[row lhi*4+q][gate g, unit])
        float h0 = lstm_cell(acc0[0], acc1[0], acc2[0], acc3[0], c[0]);
        float h1 = lstm_cell(acc0[1], acc1[1], acc2[1], acc3[1], c[1]);
        float h2 = lstm_cell(acc0[2], acc1[2], acc2[2], acc3[2], c[2]);
        float h3 = lstm_cell(acc0[3], acc1[3], acc2[3], acc3[3], c[3]);
        hq[0] = h0; hq[1] = h1; hq[2] = h2; hq[3] = h3;

        // h -> a_buf[pn] as bf16 (packed convert, strided b16 stores)
        const unsigned u01 = cvt_pk_bf16(h0, h1);
        const unsigned u23 = cvt_pk_bf16(h2, h3);
        short* const hdst = &a_buf[pn][sh][0][0] + hbank * 8 + lhi * 32 + jh;
        hdst[0]  = (short)(u01 & 0xffffu);
        hdst[8]  = (short)(u01 >> 16);
        hdst[16] = (short)(u23 & 0xffffu);
        hdst[24] = (short)(u23 >> 16);

        // x[t+1] -> a_buf[pn]
        if (t + 1 < TSTEPS) {
            short* const xdst = abase + pn * (3 * 64 * 8);
            xdst[xoff0] = (short)(cvt_pk_bf16(xv0, xv0) & 0xffffu);
            if (tid < 144) xdst[xoff1] = (short)(cvt_pk_bf16(xv1, xv1) & 0xffffu);
        }
        __syncthreads();
    }

    // ---- epilogue: logits = h_last @ fc_w + fc_b ----
    #pragma unroll
    for (int q = 0; q < 4; ++q) {
        float pq = hq[q] * fcw;
        pq += __shfl_xor(pq, 1);
        pq += __shfl_xor(pq, 2);
        pq += __shfl_xor(pq, 4);
        pq += __shfl_xor(pq, 8);
        if (lrow == 0) red[wv][lhi * 4 + q] = pq;
    }
    __syncthreads();
    if (tid < TILE_B) {
        out[row0 + tid] = red[0][tid] + red[1][tid] + red[2][tid] + red[3][tid] + fc_b[0];
    }
}

} // namespace

extern "C" void kernel_launch(void* const* d_in, const int* in_sizes, int n_in,
                              void* d_out, int out_size, void* d_ws, size_t ws_size,
                              hipStream_t stream) {
    const float* x    = (const float*)d_in[0];
    // d_in[1] = mask: all-ones, use_masked_last=False -> unused
    const float* Wx_w = (const float*)d_in[2];
    const float* Wx_b = (const float*)d_in[3];
    const float* Wh_w = (const float*)d_in[4];
    const float* Wh_b = (const float*)d_in[5];
    const float* fc_w = (const float*)d_in[6];
    const float* fc_b = (const float*)d_in[7];
    float* out = (float*)d_out;

    const int B    = out_size;        // 4096
    const int grid = B / TILE_B;      // 256 blocks = 1 per CU

    lstm_mfma<<<grid, NTHR, 0, stream>>>(x, Wx_w, Wx_b, Wh_w, Wh_b, fc_w, fc_b, out);
}

// Round 6
// 262.528 us; speedup vs baseline: 1.2840x; 1.1670x over previous
//
#include <hip/hip_runtime.h>
#include <math.h>

namespace {

constexpr int TSTEPS = 512;
constexpr int F_IN   = 25;
constexpr int H_DIM  = 64;
constexpr int TILE_B = 16;
constexpr int NTHR   = 256;
// K layout: [0,25) = x, [25,89) = h, 89 = bias-one, [90,96) = zero pad
// A-fragment buffer: [2 bufs][3 ksteps][64 lanes][8 bf16], fragment-ordered:
//   slot (s, lane, j) holds A[row = lane&15][k = s*32 + (lane>>4)*8 + j]

typedef __attribute__((ext_vector_type(8))) short bf16x8;
typedef __attribute__((ext_vector_type(4))) float f32x4;

constexpr float LOG2E  = 1.4426950408889634f;
constexpr float LOG2E2 = 2.8853900817779268f;

__device__ __forceinline__ short f2bf(float f) {  // round-to-nearest-even (setup only)
    unsigned u = __float_as_uint(f);
    unsigned r = (u + 0x7FFFu + ((u >> 16) & 1u)) >> 16;
    return (short)r;
}
__device__ __forceinline__ unsigned cvt_pk_bf16(float lo, float hi) {
    unsigned r;
    asm("v_cvt_pk_bf16_f32 %0, %1, %2" : "=v"(r) : "v"(lo), "v"(hi));
    return r;
}
__device__ __forceinline__ float exp2_neg(float x) {      // 2^(-x)
    float r;
    asm("v_exp_f32 %0, -%1" : "=v"(r) : "v"(x));
    return r;
}
__device__ __forceinline__ float exp2_negabs(float x) {   // 2^(-|x|)
    float r;
    asm("v_exp_f32 %0, -abs(%1)" : "=v"(r) : "v"(x));
    return r;
}

// Pre-scaled cell: z' = log2e*z for i,f,o ; z' = 2*log2e*z for g.
//   sigmoid(z) = 1/(1+2^-z') ; tanh pair shares denominators; 5 exp + 3 rcp.
// Limits: z -> -inf gives e=inf, rcp(inf)=0 -> gate=0 (correct, no NaN).
__device__ __forceinline__ float lstm_cell(float zi, float zf, float zg, float zo, float& c) {
    const float ei = exp2_neg(zi);
    const float ef = exp2_neg(zf);
    const float eg = exp2_negabs(zg);
    const float eo = exp2_neg(zo);
    const float r1 = __builtin_amdgcn_rcpf((1.0f + ei) * (1.0f + eg));
    const float ig = copysignf((1.0f - eg) * r1, zg);
    const float f  = __builtin_amdgcn_rcpf(1.0f + ef);
    const float cn = fmaf(c, f, ig);
    c = cn;
    const float ec = exp2_negabs(cn * LOG2E2);
    const float r3 = __builtin_amdgcn_rcpf((1.0f + eo) * (1.0f + ec));
    return copysignf((1.0f - ec) * r3, cn);
}

__global__ __launch_bounds__(NTHR)
void lstm_mfma(const float* __restrict__ x,     // [B, T, F]
               const float* __restrict__ Wx_w,  // [256, 25]
               const float* __restrict__ Wx_b,  // [256]
               const float* __restrict__ Wh_w,  // [256, 64]
               const float* __restrict__ Wh_b,  // [256]
               const float* __restrict__ fc_w,  // [64]
               const float* __restrict__ fc_b,  // [1]
               float* __restrict__ out)         // [B]
{
    __shared__ short a_buf[2][3][64][8];   // 6144 B
    __shared__ float red[4][16];

    const int tid  = threadIdx.x;
    const int l    = tid & 63;
    const int wv   = tid >> 6;       // wave id: owns units [wv*16, wv*16+16) x 4 gates
    const int lrow = l & 15;
    const int lhi  = l >> 4;
    const int row0 = blockIdx.x * TILE_B;

    // ---- W^T B-fragments (bf16 hi only, log2e pre-scaled): 12 frags = 48 VGPR ----
    bf16x8 w_hi[4][3];
    #pragma unroll
    for (int g = 0; g < 4; ++g) {
        const int col = g * 64 + wv * 16 + lrow;   // gate-col this lane serves
        const float scale = (g == 2) ? LOG2E2 : LOG2E;   // gate order i,f,g,o
        #pragma unroll
        for (int s = 0; s < 3; ++s) {
            bf16x8 hi;
            #pragma unroll
            for (int j = 0; j < 8; ++j) {
                const int k = s * 32 + lhi * 8 + j;
                float val;
                if (k < F_IN)           val = Wx_w[col * F_IN + k];
                else if (k < 89)        val = Wh_w[col * H_DIM + (k - F_IN)];
                else if (k == 89)       val = Wx_b[col] + Wh_b[col];   // fused bias
                else                    val = 0.0f;
                hi[j] = f2bf(val * scale);
            }
            w_hi[g][s] = hi;
        }
    }

    // ---- init a_buf: zeros, bias-one at k==89 (both buffers) ----
    for (int idx = tid; idx < 2 * 3 * 64 * 8; idx += NTHR) {
        const int j    = idx & 7;
        const int lane = (idx >> 3) & 63;
        const int s    = (idx >> 9) % 3;
        const int k    = s * 32 + (lane >> 4) * 8 + j;
        ((short*)a_buf)[idx] = (k == 89) ? (short)0x3F80 : (short)0;
    }
    __syncthreads();

    // ---- per-thread x slot mapping (constant across steps) ----
    // element e -> (row = e/25, f = e%25); slot: s=0, lane' = row | ((f>>3)<<4), j = f&7
    const int xrow0 = tid / F_IN,          xf0 = tid % F_IN;           // e0 = tid (<400 always)
    const int xrow1 = (tid + 256) / F_IN,  xf1 = (tid + 256) % F_IN;   // e1 valid iff tid<144
    const float* xq0 = x + (size_t)(row0 + xrow0) * TSTEPS * F_IN + xf0;
    const float* xq1 = x + (size_t)(row0 + (tid < 144 ? xrow1 : 0)) * TSTEPS * F_IN + xf1;
    const int xoff0 = ((xrow0 | ((xf0 >> 3) << 4)) * 8) + (xf0 & 7);
    const int xoff1 = ((xrow1 | ((xf1 >> 3) << 4)) * 8) + (xf1 & 7);
    short* const abase = &a_buf[0][0][0][0];

    // x[t=0] into buffer 0
    abase[xoff0] = f2bf(xq0[0]);
    if (tid < 144) abase[xoff1] = f2bf(xq1[0]);
    __syncthreads();

    // advance prefetch pointers to t=1
    xq0 += F_IN;
    xq1 += F_IN;

    // ---- h-write slot mapping (constant): k = 25 + unit ----
    const int unit  = wv * 16 + lrow;
    const int kh    = F_IN + unit;
    const int sh    = kh >> 5;
    const int hbank = ((kh >> 3) & 3) << 4;
    const int jh    = kh & 7;

    const float fcw = fc_w[unit];
    float c[4] = {0.f, 0.f, 0.f, 0.f};
    float hq[4] = {0.f, 0.f, 0.f, 0.f};

    const f32x4 czero = {0.f, 0.f, 0.f, 0.f};

    for (int t = 0; t < TSTEPS; ++t) {
        const int p  = t & 1;
        const int pn = p ^ 1;

        // A fragments (conflict-free b128, all waves broadcast-read same region)
        bf16x8 a0 = *(const bf16x8*)&a_buf[p][0][l][0];
        bf16x8 a1 = *(const bf16x8*)&a_buf[p][1][l][0];
        bf16x8 a2 = *(const bf16x8*)&a_buf[p][2][l][0];

        // prefetch x[t+1] (latency hides under MFMA + gates)
        float xv0 = 0.f, xv1 = 0.f;
        if (t + 1 < TSTEPS) {
            xv0 = xq0[0];
            if (tid < 144) xv1 = xq1[0];
            xq0 += F_IN;
            xq1 += F_IN;
        }

        // z' = v @ W'^T, 12 MFMAs (bf16-W only; MFMA region is throughput-
        // bound at ~19 cyc/MFMA/SIMD, so count is the cost). 4 indep chains.
        f32x4 acc0, acc1, acc2, acc3;
        acc0 = __builtin_amdgcn_mfma_f32_16x16x32_bf16(a0, w_hi[0][0], czero, 0, 0, 0);
        acc1 = __builtin_amdgcn_mfma_f32_16x16x32_bf16(a0, w_hi[1][0], czero, 0, 0, 0);
        acc2 = __builtin_amdgcn_mfma_f32_16x16x32_bf16(a0, w_hi[2][0], czero, 0, 0, 0);
        acc3 = __builtin_amdgcn_mfma_f32_16x16x32_bf16(a0, w_hi[3][0], czero, 0, 0, 0);

        acc0 = __builtin_amdgcn_mfma_f32_16x16x32_bf16(a1, w_hi[0][1], acc0, 0, 0, 0);
        acc1 = __builtin_amdgcn_mfma_f32_16x16x32_bf16(a1, w_hi[1][1], acc1, 0, 0, 0);
        acc2 = __builtin_amdgcn_mfma_f32_16x16x32_bf16(a1, w_hi[2][1], acc2, 0, 0, 0);
        acc3 = __builtin_amdgcn_mfma_f32_16x16x32_bf16(a1, w_hi[3][1], acc3, 0, 0, 0);

        acc0 = __builtin_amdgcn_mfma_f32_16x16x32_bf16(a2, w_hi[0][2], acc0, 0, 0, 0);
        acc1 = __builtin_amdgcn_mfma_f32_16x16x32_bf16(a2, w_hi[1][2], acc1, 0, 0, 0);
        acc2 = __builtin_amdgcn_mfma_f32_16x16x32_bf16(a2, w_hi[2][2], acc2, 0, 0, 0);
        acc3 = __builtin_amdgcn_mfma_f32_16x16x32_bf16(a2, w_hi[3][2], acc3, 0, 0, 0);

        // gates + c/h update (acc_g[q] = z'[row lhi*4+q][gate g, unit])
        float h0 = lstm_cell(acc0[0], acc1[0], acc2[0], acc3[0], c[0]);
        float h1 = lstm_cell(acc0[1], acc1[1], acc2[1], acc3[1], c[1]);
        float h2 = lstm_cell(acc0[2], acc1[2], acc2[2], acc3[2], c[2]);
        float h3 = lstm_cell(acc0[3], acc1[3], acc2[3], acc3[3], c[3]);
        hq[0] = h0; hq[1] = h1; hq[2] = h2; hq[3] = h3;

        // h -> a_buf[pn] as bf16 (packed convert, strided b16 stores)
        const unsigned u01 = cvt_pk_bf16(h0, h1);
        const unsigned u23 = cvt_pk_bf16(h2, h3);
        short* const hdst = &a_buf[pn][sh][0][0] + hbank * 8 + lhi * 32 + jh;
        hdst[0]  = (short)(u01 & 0xffffu);
        hdst[8]  = (short)(u01 >> 16);
        hdst[16] = (short)(u23 & 0xffffu);
        hdst[24] = (short)(u23 >> 16);

        // x[t+1] -> a_buf[pn]
        if (t + 1 < TSTEPS) {
            short* const xdst = abase + pn * (3 * 64 * 8);
            xdst[xoff0] = (short)(cvt_pk_bf16(xv0, xv0) & 0xffffu);
            if (tid < 144) xdst[xoff1] = (short)(cvt_pk_bf16(xv1, xv1) & 0xffffu);
        }
        __syncthreads();
    }

    // ---- epilogue: logits = h_last @ fc_w + fc_b ----
    #pragma unroll
    for (int q = 0; q < 4; ++q) {
        float pq = hq[q] * fcw;
        pq += __shfl_xor(pq, 1);
        pq += __shfl_xor(pq, 2);
        pq += __shfl_xor(pq, 4);
        pq += __shfl_xor(pq, 8);
        if (lrow == 0) red[wv][lhi * 4 + q] = pq;
    }
    __syncthreads();
    if (tid < TILE_B) {
        out[row0 + tid] = red[0][tid] + red[1][tid] + red[2][tid] + red[3][tid] + fc_b[0];
    }
}

} // namespace

extern "C" void kernel_launch(void* const* d_in, const int* in_sizes, int n_in,
                              void* d_out, int out_size, void* d_ws, size_t ws_size,
                              hipStream_t stream) {
    const float* x    = (const float*)d_in[0];
    // d_in[1] = mask: all-ones, use_masked_last=False -> unused
    const float* Wx_w = (const float*)d_in[2];
    const float* Wx_b = (const float*)d_in[3];
    const float* Wh_w = (const float*)d_in[4];
    const float* Wh_b = (const float*)d_in[5];
    const float* fc_w = (const float*)d_in[6];
    const float* fc_b = (const float*)d_in[7];
    float* out = (float*)d_out;

    const int B    = out_size;        // 4096
    const int grid = B / TILE_B;      // 256 blocks = 1 per CU

    lstm_mfma<<<grid, NTHR, 0, stream>>>(x, Wx_w, Wx_b, Wh_w, Wh_b, fc_w, fc_b, out);
}